// Round 15
// baseline (990.338 us; speedup 1.0000x reference)
//
#include <hip/hip_runtime.h>
#include <math.h>

// Problem constants (from reference setup_inputs)
constexpr int N    = 50000;   // nodes
constexpr int E    = 800000;  // edges
constexpr int CIN  = 100;     // input channels
constexpr int CH   = 128;     // hidden channels
constexpr int COUT = 47;      // output channels
constexpr int NOUT = 25000;   // original_size (rows emitted)
constexpr int CP   = 48;      // COUT padded (storage stride)
constexpr int NB   = (N + 255) / 256;   // 196 scan chunks
constexpr int TN   = 128;               // gemm tile nodes (R11 proven best)
constexpr int NT   = (N + TN - 1) / TN; // 391 gemm blocks
constexpr int HS4  = 33;  // hbuf stride in float4 (132 floats)
constexpr int FS4  = 9;   // fbuf stride in float4 (36 floats)
constexpr int CSRB = 1024; // coop grid: 4 blocks/CU (residency cap is 8 -> safe)

// ---------------------------------------------------------------------------
// Manual device-scope grid barrier. R14 post-mortem: cg::grid_group::sync()
// costs ~40us/sync on gfx950 (csr_build 343us at VALUBusy 0.17%). This is the
// classic arrive+generation barrier: one atomic add per block, spin on gen
// with s_sleep backoff. bar[0]=arrive count, bar[1]=generation (both zeroed
// by the host-side memset before launch). Release/acquire via __hip_atomic_*
// at agent scope gives cross-XCD visibility of pre-barrier writes.
__device__ __forceinline__ void grid_barrier(int* bar, int nblocks) {
    __syncthreads();
    if (threadIdx.x == 0) {
        __threadfence();                                     // publish writes
        int* cnt = bar;
        int* gen = bar + 1;
        int g = __hip_atomic_load(gen, __ATOMIC_RELAXED, __HIP_MEMORY_SCOPE_AGENT);
        int prev = __hip_atomic_fetch_add(cnt, 1, __ATOMIC_ACQ_REL,
                                          __HIP_MEMORY_SCOPE_AGENT);
        if (prev == nblocks - 1) {
            __hip_atomic_store(cnt, 0, __ATOMIC_RELAXED, __HIP_MEMORY_SCOPE_AGENT);
            __hip_atomic_fetch_add(gen, 1, __ATOMIC_ACQ_REL,
                                   __HIP_MEMORY_SCOPE_AGENT);   // release
        } else {
            while (__hip_atomic_load(gen, __ATOMIC_ACQUIRE,
                                     __HIP_MEMORY_SCOPE_AGENT) == g)
                __builtin_amdgcn_s_sleep(8);
        }
        __threadfence();
    }
    __syncthreads();
}

// ---------------------------------------------------------------------------
// R15: one cooperative kernel = w2cat pad + hist + scan + apply + fill +
// gather1 (7 dispatches -> 1; boundaries were ~10us each). Phases split by
// the manual barrier above. 1024 blocks x 256 thr.
__global__ __launch_bounds__(256) void csr_gather(
        const float* __restrict__ x,
        const int* __restrict__ src, const int* __restrict__ dst,
        int* __restrict__ cnt, int* __restrict__ bar,
        int* __restrict__ row_ptr, int* __restrict__ cursor,
        int* __restrict__ blkSum, int* __restrict__ col,
        const float* __restrict__ w2l, const float* __restrict__ w2r,
        const float* __restrict__ b2l, float* __restrict__ w2cat,
        float* __restrict__ b2cat, float* __restrict__ agg1) {
    __shared__ int s[256];
    int t = threadIdx.x, bid = blockIdx.x;
    int gid = bid * 256 + t;
    const int gsz = CSRB * 256;

    // phase 0: padded layer-2 weights (consumed by the NEXT kernel; no barrier
    // needed for it). cnt/bar already zeroed by host memset.
    for (int j = gid; j < CH * 128; j += gsz) {
        int k = j >> 7, c = j & 127;
        float v = 0.0f;
        if (c < COUT)                      v = w2l[k * COUT + c];
        else if (c >= 64 && c < 64 + COUT) v = w2r[k * COUT + (c - 64)];
        w2cat[j] = v;
    }
    if (gid < 128) b2cat[gid] = (gid >= 64 && gid < 64 + COUT) ? b2l[gid - 64] : 0.0f;

    // phase 1: in-degree histogram
    for (int i = gid; i < E; i += gsz) atomicAdd(&cnt[dst[i]], 1);
    grid_barrier(bar, CSRB);

    // phase 2: per-chunk exclusive scan (blocks 0..NB-1)
    if (bid < NB) {
        int i = bid * 256 + t;
        int v = (i < N) ? cnt[i] : 0;
        s[t] = v;
        __syncthreads();
        for (int off = 1; off < 256; off <<= 1) {
            int a = s[t];
            int u = (t >= off) ? s[t - off] : 0;
            __syncthreads();
            s[t] = a + u;
            __syncthreads();
        }
        if (i < N) row_ptr[i] = s[t] - v;        // chunk-local exclusive
        if (t == 255) blkSum[bid] = s[255];      // chunk total
    }
    grid_barrier(bar, CSRB);

    // phase 3: block 0 turns blkSum into exclusive offsets (NB=196 <= 256)
    if (bid == 0) {
        int v = (t < NB) ? blkSum[t] : 0;
        s[t] = v;
        __syncthreads();
        for (int off = 1; off < 256; off <<= 1) {
            int a = s[t];
            int u = (t >= off) ? s[t - off] : 0;
            __syncthreads();
            s[t] = a + u;
            __syncthreads();
        }
        if (t < NB) blkSum[t] = s[t] - v;        // exclusive, in place
    }
    grid_barrier(bar, CSRB);

    // phase 4: apply offsets; cursor copy; terminator
    if (bid < NB) {
        int i = bid * 256 + t;
        if (i < N) {
            int v = row_ptr[i] + blkSum[bid];
            row_ptr[i] = v;
            cursor[i]  = v;
            if (i == N - 1) row_ptr[N] = E;
        }
    }
    grid_barrier(bar, CSRB);

    // phase 5: bucket-fill edge sources
    for (int i = gid; i < E; i += gsz) {
        int d = dst[i];
        int p = atomicAdd(&cursor[d], 1);
        col[p] = src[i];
    }
    grid_barrier(bar, CSRB);

    // phase 6: gather1 — agg1[n] = mean of neighbor x rows. Half-wave per
    // node; lane l<25 owns one f4 of the 400B row; unroll-4 chains.
    {
        int hw = gid >> 5;                 // global half-wave id
        int l  = t & 31;
        const int nHW = gsz >> 5;          // 8192 half-waves
        const float4* xb = (const float4*)x;
        for (int n = hw; n < N; n += nHW) {
            int b = row_ptr[n], e = row_ptr[n + 1];
            float inv = 1.0f / (float)max(e - b, 1);
            if (l < 25) {
                float4 s0 = make_float4(0.f, 0.f, 0.f, 0.f);
                float4 s1 = s0, s2 = s0, s3 = s0;
                int j = b;
                for (; j + 3 < e; j += 4) {
                    float4 v0 = xb[(size_t)col[j]     * 25 + l];
                    float4 v1 = xb[(size_t)col[j + 1] * 25 + l];
                    float4 v2 = xb[(size_t)col[j + 2] * 25 + l];
                    float4 v3 = xb[(size_t)col[j + 3] * 25 + l];
                    s0.x += v0.x; s0.y += v0.y; s0.z += v0.z; s0.w += v0.w;
                    s1.x += v1.x; s1.y += v1.y; s1.z += v1.z; s1.w += v1.w;
                    s2.x += v2.x; s2.y += v2.y; s2.z += v2.z; s2.w += v2.w;
                    s3.x += v3.x; s3.y += v3.y; s3.z += v3.z; s3.w += v3.w;
                }
                for (; j < e; ++j) {
                    float4 v = xb[(size_t)col[j] * 25 + l];
                    s0.x += v.x; s0.y += v.y; s0.z += v.z; s0.w += v.w;
                }
                ((float4*)agg1)[(size_t)n * 25 + l] = make_float4(
                    ((s0.x + s1.x) + (s2.x + s3.x)) * inv,
                    ((s0.y + s1.y) + (s2.y + s3.y)) * inv,
                    ((s0.z + s1.z) + (s2.z + s3.z)) * inv,
                    ((s0.w + s1.w) + (s2.w + s3.w)) * inv);
            }
        }
    }
}

// ---------------------------------------------------------------------------
// fused gemm — exact R11 structure (best measured: 80us). 256thr/4 waves,
// TN=128; roles nodeHalf x chHalf; 8x8 lane tile. LDS 81,920B -> 2 blocks/CU.
__global__ __launch_bounds__(256) void fused_gemm(
        const float* __restrict__ agg1, const float* __restrict__ x,
        const float* __restrict__ w1l, const float* __restrict__ b1l,
        const float* __restrict__ w1r,
        const float* __restrict__ w2cat, const float* __restrict__ b2cat,
        float* __restrict__ gsrc, float* __restrict__ gself) {
    __shared__ float lds[TN * 132 + 28 * CH];   // 20480 floats = 81920 B
    float4* hbuf4 = (float4*)lds;               // stride HS4=33 f4
    float4* fbuf4 = (float4*)lds;               // stride FS4=9 f4, dead pre-hbuf
    float4* wbuf4 = (float4*)(lds + TN * 132);  // 896 f4

    int t = threadIdx.x;
    int base = blockIdx.x * TN;
    int lane = t & 63;
    int wv = __builtin_amdgcn_readfirstlane(t >> 6);  // 0..3
    int nh  = wv & 1;
    int chh = wv >> 1;
    int m_l = lane & 7;
    int c_l = lane >> 3;
    int row0 = nh * 64 + m_l;
    int nmax = N - 1 - base; if (nmax > TN - 1) nmax = TN - 1;

    float a[8][8];
    #pragma unroll
    for (int q = 0; q < 8; ++q) {
        float bv = b1l[chh * 64 + c_l * 8 + q];
        #pragma unroll
        for (int im = 0; im < 8; ++im) a[im][q] = bv;
    }

    // ---- stage 1: h = agg1@w1l + x@w1r + b1l ; chunks 28,28,28,16
    for (int ph = 0; ph < 2; ++ph) {
        const float* F = ph ? x : agg1;
        const float* W = ph ? w1r : w1l;
        for (int ci = 0; ci < 4; ++ci) {
            int k0 = ci * 28;
            int kc = (ci == 3) ? 16 : 28;
            int kc4 = kc >> 2;                       // 7 or 4
            for (int i = t; i < TN * kc4; i += 256) {
                int row = i / kc4, j = i - row * kc4;
                int rr = row <= nmax ? row : nmax;
                fbuf4[row * FS4 + j] =
                    *(const float4*)(F + (size_t)(base + rr) * CIN + k0 + j * 4);
            }
            for (int i = t; i < kc * 32; i += 256) {
                int k = i >> 5, jj = i & 31;
                wbuf4[i] = *(const float4*)(W + (size_t)(k0 + k) * CH + jj * 4);
            }
            __syncthreads();
            for (int kg = 0; kg < kc4; ++kg) {
                float4 f[8];
                #pragma unroll
                for (int im = 0; im < 8; ++im)
                    f[im] = fbuf4[(row0 + 8 * im) * FS4 + kg];
                #pragma unroll
                for (int j = 0; j < 4; ++j) {
                    float4 w0 = wbuf4[(kg * 4 + j) * 32 + chh * 16 + c_l * 2 + 0];
                    float4 w1 = wbuf4[(kg * 4 + j) * 32 + chh * 16 + c_l * 2 + 1];
                    #pragma unroll
                    for (int im = 0; im < 8; ++im) {
                        float fv = (j == 0) ? f[im].x : (j == 1) ? f[im].y
                                 : (j == 2) ? f[im].z : f[im].w;
                        a[im][0] = fmaf(fv, w0.x, a[im][0]);
                        a[im][1] = fmaf(fv, w0.y, a[im][1]);
                        a[im][2] = fmaf(fv, w0.z, a[im][2]);
                        a[im][3] = fmaf(fv, w0.w, a[im][3]);
                        a[im][4] = fmaf(fv, w1.x, a[im][4]);
                        a[im][5] = fmaf(fv, w1.y, a[im][5]);
                        a[im][6] = fmaf(fv, w1.z, a[im][6]);
                        a[im][7] = fmaf(fv, w1.w, a[im][7]);
                    }
                }
            }
            __syncthreads();
        }
    }
    #pragma unroll
    for (int im = 0; im < 8; ++im) {
        hbuf4[(row0 + 8 * im) * HS4 + chh * 16 + c_l * 2 + 0] =
            make_float4(a[im][0], a[im][1], a[im][2], a[im][3]);
        hbuf4[(row0 + 8 * im) * HS4 + chh * 16 + c_l * 2 + 1] =
            make_float4(a[im][4], a[im][5], a[im][6], a[im][7]);
    }
    __syncthreads();

    // ---- stage 2: [gsrc|gself] = h @ w2cat (+ b2cat) ; k-chunks of 16
    #pragma unroll
    for (int q = 0; q < 8; ++q) {
        float bv = b2cat[chh * 64 + c_l * 8 + q];
        #pragma unroll
        for (int im = 0; im < 8; ++im) a[im][q] = bv;
    }
    bool skip = (chh == 1) && (base >= NOUT);
    for (int k0 = 0; k0 < CH; k0 += 16) {
        for (int i = t; i < 512; i += 256)
            wbuf4[i] = *(const float4*)(w2cat + (size_t)(k0 + (i >> 5)) * 128
                                        + (i & 31) * 4);
        __syncthreads();
        if (!skip) {
            for (int kg = 0; kg < 4; ++kg) {
                float4 f[8];
                #pragma unroll
                for (int im = 0; im < 8; ++im)
                    f[im] = hbuf4[(row0 + 8 * im) * HS4 + (k0 >> 2) + kg];
                #pragma unroll
                for (int j = 0; j < 4; ++j) {
                    float4 w0 = wbuf4[(kg * 4 + j) * 32 + chh * 16 + c_l * 2 + 0];
                    float4 w1 = wbuf4[(kg * 4 + j) * 32 + chh * 16 + c_l * 2 + 1];
                    #pragma unroll
                    for (int im = 0; im < 8; ++im) {
                        float fv = (j == 0) ? f[im].x : (j == 1) ? f[im].y
                                 : (j == 2) ? f[im].z : f[im].w;
                        a[im][0] = fmaf(fv, w0.x, a[im][0]);
                        a[im][1] = fmaf(fv, w0.y, a[im][1]);
                        a[im][2] = fmaf(fv, w0.z, a[im][2]);
                        a[im][3] = fmaf(fv, w0.w, a[im][3]);
                        a[im][4] = fmaf(fv, w1.x, a[im][4]);
                        a[im][5] = fmaf(fv, w1.y, a[im][5]);
                        a[im][6] = fmaf(fv, w1.z, a[im][6]);
                        a[im][7] = fmaf(fv, w1.w, a[im][7]);
                    }
                }
            }
        }
        __syncthreads();
    }
    if (!skip && c_l < 6) {
        float* G = (wv >> 1) ? gself : gsrc;
        int lim = (wv >> 1) ? NOUT : N;
        #pragma unroll
        for (int im = 0; im < 8; ++im) {
            int n = base + row0 + 8 * im;
            if (n < lim) {
                *(float4*)(G + (size_t)n * CP + c_l * 8) =
                    make_float4(a[im][0], a[im][1], a[im][2], a[im][3]);
                *(float4*)(G + (size_t)n * CP + c_l * 8 + 4) =
                    make_float4(a[im][4], a[im][5], a[im][6], a[im][7]);
            }
        }
    }
}

// ---------------------------------------------------------------------------
// final v2: unroll-4 gather of gsrc rows + fused log_softmax.
__global__ __launch_bounds__(64) void final_kernel(const float* __restrict__ gsrc,
        const float* __restrict__ gself, const int* __restrict__ row_ptr,
        const int* __restrict__ col, float* __restrict__ out) {
    int n = blockIdx.x;
    int c = threadIdx.x;
    int b = row_ptr[n], e = row_ptr[n + 1];
    float inv = 1.0f / (float)max(e - b, 1);
    float a0 = 0.f, a1 = 0.f, a2 = 0.f, a3 = 0.f;
    if (c < CP) {
        int j = b;
        for (; j + 3 < e; j += 4) {
            a0 += gsrc[(size_t)col[j]     * CP + c];
            a1 += gsrc[(size_t)col[j + 1] * CP + c];
            a2 += gsrc[(size_t)col[j + 2] * CP + c];
            a3 += gsrc[(size_t)col[j + 3] * CP + c];
        }
        for (; j < e; ++j) a0 += gsrc[(size_t)col[j] * CP + c];
    }
    float val = (c < COUT)
        ? (((a0 + a1) + (a2 + a3)) * inv + gself[(size_t)n * CP + c]) : -INFINITY;
    float m = val;
    #pragma unroll
    for (int off = 32; off > 0; off >>= 1) m = fmaxf(m, __shfl_xor(m, off, 64));
    float ex = (c < COUT) ? expf(val - m) : 0.f;
    float ssum = ex;
    #pragma unroll
    for (int off = 32; off > 0; off >>= 1) ssum += __shfl_xor(ssum, off, 64);
    if (c < COUT) out[(size_t)n * COUT + c] = val - m - logf(ssum);
}

// ---------------------------------------------------------------------------
extern "C" void kernel_launch(void* const* d_in, const int* in_sizes, int n_in,
                              void* d_out, int out_size, void* d_ws, size_t ws_size,
                              hipStream_t stream) {
    const float* x   = (const float*)d_in[0];
    const int*   ei  = (const int*)d_in[1];   // [2, E]: row 0 = src, row 1 = dst
    const int*   src = ei;
    const int*   dst = ei + E;
    const float* w1l = (const float*)d_in[3];
    const float* b1l = (const float*)d_in[4];
    const float* w1r = (const float*)d_in[5];
    const float* w2l = (const float*)d_in[6];
    const float* b2l = (const float*)d_in[7];
    const float* w2r = (const float*)d_in[8];
    float* out = (float*)d_out;

    // ws: ints [cnt N | bar 2 | row_ptr N+1 | cursor N | blkSum NB | col E]
    // floats [agg1 N*CIN | gsrc N*CP | gself NOUT*CP | w2cat CH*128 | b2cat 128]
    int* cnt     = (int*)d_ws;
    int* bar     = cnt + N;                  // 2 ints of barrier state
    int* row_ptr = bar + 2;
    int* cursor  = row_ptr + N + 1;
    int* blkSum  = cursor + N;
    int* col     = blkSum + NB;
    size_t intWords = (size_t)N + 2 + (N + 1) + N + NB + E;
    intWords = (intWords + 3) & ~(size_t)3;
    float* agg1  = (float*)d_ws + intWords;
    float* gsrc  = agg1 + (size_t)N * CIN;
    float* gself = gsrc + (size_t)N * CP;
    float* w2cat = gself + (size_t)NOUT * CP;
    float* b2cat = w2cat + (size_t)CH * 128;
    // total ws ~38.4 MB (< 58.6 MB proven available)

    // zero cnt + barrier state in one memset
    hipMemsetAsync(cnt, 0, ((size_t)N + 2) * sizeof(int), stream);

    // one cooperative launch: w2 pad + hist + scan + apply + fill + gather1
    {
        void* args[] = {(void*)&x, (void*)&src, (void*)&dst, (void*)&cnt,
                        (void*)&bar, (void*)&row_ptr, (void*)&cursor,
                        (void*)&blkSum, (void*)&col,
                        (void*)&w2l, (void*)&w2r, (void*)&b2l,
                        (void*)&w2cat, (void*)&b2cat, (void*)&agg1};
        hipLaunchCooperativeKernel((const void*)csr_gather, dim3(CSRB), dim3(256),
                                   args, 0, stream);
    }
    fused_gemm  <<<NT, 256, 0, stream>>>(agg1, x, w1l, b1l, w1r,
                                         w2cat, b2cat, gsrc, gself);
    final_kernel<<<NOUT, 64, 0, stream>>>(gsrc, gself, row_ptr, col, out);
}

// Round 16
// 340.154 us; speedup vs baseline: 2.9114x; 2.9114x over previous
//
#include <hip/hip_runtime.h>
#include <math.h>

// Problem constants (from reference setup_inputs)
constexpr int N    = 50000;   // nodes
constexpr int E    = 800000;  // edges
constexpr int CIN  = 100;     // input channels
constexpr int CH   = 128;     // hidden channels
constexpr int COUT = 47;      // output channels
constexpr int NOUT = 25000;   // original_size (rows emitted)
constexpr int CP   = 48;      // COUT padded (storage stride)
constexpr int NB   = (N + 255) / 256;   // 196 scan chunks
constexpr int EB   = (E + 255) / 256;   // 3125 edge blocks
constexpr int PADB = (CH * 128 + 255) / 256; // 64 pad blocks
constexpr int TN   = 128;               // gemm tile nodes (R11 proven best)
constexpr int NT   = (N + TN - 1) / TN; // 391 gemm blocks
constexpr int HS4  = 33;  // hbuf stride in float4 (132 floats)
constexpr int FS4  = 9;   // fbuf stride in float4 (36 floats)

// ---------------------------------------------------------------------------
// hist + w2cat pad in one dispatch (independent work, disjoint blocks).
__global__ __launch_bounds__(256) void hist_pad(const int* __restrict__ dst,
        int* __restrict__ cnt,
        const float* __restrict__ w2l, const float* __restrict__ w2r,
        const float* __restrict__ b2l, float* __restrict__ w2cat,
        float* __restrict__ b2cat) {
    int bid = blockIdx.x, t = threadIdx.x;
    if (bid < EB) {
        int i = bid * 256 + t;
        if (i < E) atomicAdd(&cnt[dst[i]], 1);
    } else {
        int j = (bid - EB) * 256 + t;
        if (j < CH * 128) {
            int k = j >> 7, c = j & 127;
            float v = 0.0f;
            if (c < COUT)                      v = w2l[k * COUT + c];
            else if (c >= 64 && c < 64 + COUT) v = w2r[k * COUT + (c - 64)];
            w2cat[j] = v;
        }
        if (j < 128) b2cat[j] = (j >= 64 && j < 64 + COUT) ? b2l[j - 64] : 0.0f;
    }
}

// ---------------------------------------------------------------------------
// scan_one (R16): merges scan_blocks+scan_apply. Each block redundantly sums
// cnt[0..base) itself (<=50k L2-hit reads, trivial) then chunk-scans in LDS.
// No cross-block dependency -> single dispatch, no blkSum array.
__global__ __launch_bounds__(256) void scan_one(const int* __restrict__ cnt,
        int* __restrict__ row_ptr, int* __restrict__ cursor) {
    __shared__ int s[256];
    int t = threadIdx.x, bid = blockIdx.x;
    int start = bid * 256;
    // block-wide sum of all preceding counts
    int acc = 0;
    for (int i = t; i < start; i += 256) acc += cnt[i];
    s[t] = acc;
    __syncthreads();
    for (int off = 128; off > 0; off >>= 1) {
        if (t < off) s[t] += s[t + off];
        __syncthreads();
    }
    int offset = s[0];
    __syncthreads();                       // s[] reused below
    // chunk-local exclusive scan
    int i = start + t;
    int v = (i < N) ? cnt[i] : 0;
    s[t] = v;
    __syncthreads();
    for (int off = 1; off < 256; off <<= 1) {
        int a = s[t];
        int u = (t >= off) ? s[t - off] : 0;
        __syncthreads();
        s[t] = a + u;
        __syncthreads();
    }
    if (i < N) {
        int r = offset + s[t] - v;
        row_ptr[i] = r;
        cursor[i]  = r;
        if (i == N - 1) row_ptr[N] = E;
    }
}

// ---------------------------------------------------------------------------
// fill: bucket-fill edge sources (int atomics on cursors)
__global__ void fill_kernel(const int* __restrict__ src, const int* __restrict__ dst,
        int* __restrict__ cursor, int* __restrict__ col) {
    int i = blockIdx.x * blockDim.x + threadIdx.x;
    if (i < E) {
        int d = dst[i];
        int p = atomicAdd(&cursor[d], 1);
        col[p] = src[i];
    }
}

// ---------------------------------------------------------------------------
// gather1 v3: half-wave per node, lane l<25 owns one f4 of the 400B row;
// unroll-4 neighbor loop (4 independent chains) on the L3-latency gather.
__global__ __launch_bounds__(256) void gather1_kernel(const float* __restrict__ x,
        const int* __restrict__ row_ptr, const int* __restrict__ col,
        float* __restrict__ agg1) {
    int t = threadIdx.x;
    int n = blockIdx.x * 8 + (t >> 5);
    int l = t & 31;
    int b = row_ptr[n], e = row_ptr[n + 1];
    float inv = 1.0f / (float)max(e - b, 1);
    if (l >= 25) return;
    const float4* xb = (const float4*)x;
    float4 s0 = make_float4(0.f, 0.f, 0.f, 0.f);
    float4 s1 = s0, s2 = s0, s3 = s0;
    int j = b;
    for (; j + 3 < e; j += 4) {
        float4 v0 = xb[(size_t)col[j]     * 25 + l];
        float4 v1 = xb[(size_t)col[j + 1] * 25 + l];
        float4 v2 = xb[(size_t)col[j + 2] * 25 + l];
        float4 v3 = xb[(size_t)col[j + 3] * 25 + l];
        s0.x += v0.x; s0.y += v0.y; s0.z += v0.z; s0.w += v0.w;
        s1.x += v1.x; s1.y += v1.y; s1.z += v1.z; s1.w += v1.w;
        s2.x += v2.x; s2.y += v2.y; s2.z += v2.z; s2.w += v2.w;
        s3.x += v3.x; s3.y += v3.y; s3.z += v3.z; s3.w += v3.w;
    }
    for (; j < e; ++j) {
        float4 v = xb[(size_t)col[j] * 25 + l];
        s0.x += v.x; s0.y += v.y; s0.z += v.z; s0.w += v.w;
    }
    ((float4*)agg1)[(size_t)n * 25 + l] = make_float4(
        ((s0.x + s1.x) + (s2.x + s3.x)) * inv,
        ((s0.y + s1.y) + (s2.y + s3.y)) * inv,
        ((s0.z + s1.z) + (s2.z + s3.z)) * inv,
        ((s0.w + s1.w) + (s2.w + s3.w)) * inv);
}

// ---------------------------------------------------------------------------
// fused gemm — exact R11 structure (best measured: 80us, VALUBusy 37%).
// 256thr/4 waves, TN=128; roles nodeHalf x chHalf; 8x8 lane tile (E=0.0117).
// LDS 81,920B -> 2 blocks/CU. R13 reg-prefetch and R14/R15 coop experiments
// all regressed; this is the keeper.
__global__ __launch_bounds__(256) void fused_gemm(
        const float* __restrict__ agg1, const float* __restrict__ x,
        const float* __restrict__ w1l, const float* __restrict__ b1l,
        const float* __restrict__ w1r,
        const float* __restrict__ w2cat, const float* __restrict__ b2cat,
        float* __restrict__ gsrc, float* __restrict__ gself) {
    __shared__ float lds[TN * 132 + 28 * CH];   // 20480 floats = 81920 B
    float4* hbuf4 = (float4*)lds;               // stride HS4=33 f4
    float4* fbuf4 = (float4*)lds;               // stride FS4=9 f4, dead pre-hbuf
    float4* wbuf4 = (float4*)(lds + TN * 132);  // 896 f4

    int t = threadIdx.x;
    int base = blockIdx.x * TN;
    int lane = t & 63;
    int wv = __builtin_amdgcn_readfirstlane(t >> 6);  // 0..3
    int nh  = wv & 1;
    int chh = wv >> 1;
    int m_l = lane & 7;
    int c_l = lane >> 3;
    int row0 = nh * 64 + m_l;
    int nmax = N - 1 - base; if (nmax > TN - 1) nmax = TN - 1;

    float a[8][8];
    #pragma unroll
    for (int q = 0; q < 8; ++q) {
        float bv = b1l[chh * 64 + c_l * 8 + q];
        #pragma unroll
        for (int im = 0; im < 8; ++im) a[im][q] = bv;
    }

    // ---- stage 1: h = agg1@w1l + x@w1r + b1l ; chunks 28,28,28,16
    for (int ph = 0; ph < 2; ++ph) {
        const float* F = ph ? x : agg1;
        const float* W = ph ? w1r : w1l;
        for (int ci = 0; ci < 4; ++ci) {
            int k0 = ci * 28;
            int kc = (ci == 3) ? 16 : 28;
            int kc4 = kc >> 2;                       // 7 or 4
            for (int i = t; i < TN * kc4; i += 256) {
                int row = i / kc4, j = i - row * kc4;
                int rr = row <= nmax ? row : nmax;
                fbuf4[row * FS4 + j] =
                    *(const float4*)(F + (size_t)(base + rr) * CIN + k0 + j * 4);
            }
            for (int i = t; i < kc * 32; i += 256) {
                int k = i >> 5, jj = i & 31;
                wbuf4[i] = *(const float4*)(W + (size_t)(k0 + k) * CH + jj * 4);
            }
            __syncthreads();
            for (int kg = 0; kg < kc4; ++kg) {
                float4 f[8];
                #pragma unroll
                for (int im = 0; im < 8; ++im)
                    f[im] = fbuf4[(row0 + 8 * im) * FS4 + kg];
                #pragma unroll
                for (int j = 0; j < 4; ++j) {
                    float4 w0 = wbuf4[(kg * 4 + j) * 32 + chh * 16 + c_l * 2 + 0];
                    float4 w1 = wbuf4[(kg * 4 + j) * 32 + chh * 16 + c_l * 2 + 1];
                    #pragma unroll
                    for (int im = 0; im < 8; ++im) {
                        float fv = (j == 0) ? f[im].x : (j == 1) ? f[im].y
                                 : (j == 2) ? f[im].z : f[im].w;
                        a[im][0] = fmaf(fv, w0.x, a[im][0]);
                        a[im][1] = fmaf(fv, w0.y, a[im][1]);
                        a[im][2] = fmaf(fv, w0.z, a[im][2]);
                        a[im][3] = fmaf(fv, w0.w, a[im][3]);
                        a[im][4] = fmaf(fv, w1.x, a[im][4]);
                        a[im][5] = fmaf(fv, w1.y, a[im][5]);
                        a[im][6] = fmaf(fv, w1.z, a[im][6]);
                        a[im][7] = fmaf(fv, w1.w, a[im][7]);
                    }
                }
            }
            __syncthreads();
        }
    }
    #pragma unroll
    for (int im = 0; im < 8; ++im) {
        hbuf4[(row0 + 8 * im) * HS4 + chh * 16 + c_l * 2 + 0] =
            make_float4(a[im][0], a[im][1], a[im][2], a[im][3]);
        hbuf4[(row0 + 8 * im) * HS4 + chh * 16 + c_l * 2 + 1] =
            make_float4(a[im][4], a[im][5], a[im][6], a[im][7]);
    }
    __syncthreads();

    // ---- stage 2: [gsrc|gself] = h @ w2cat (+ b2cat) ; k-chunks of 16
    #pragma unroll
    for (int q = 0; q < 8; ++q) {
        float bv = b2cat[chh * 64 + c_l * 8 + q];
        #pragma unroll
        for (int im = 0; im < 8; ++im) a[im][q] = bv;
    }
    bool skip = (chh == 1) && (base >= NOUT);
    for (int k0 = 0; k0 < CH; k0 += 16) {
        for (int i = t; i < 512; i += 256)
            wbuf4[i] = *(const float4*)(w2cat + (size_t)(k0 + (i >> 5)) * 128
                                        + (i & 31) * 4);
        __syncthreads();
        if (!skip) {
            for (int kg = 0; kg < 4; ++kg) {
                float4 f[8];
                #pragma unroll
                for (int im = 0; im < 8; ++im)
                    f[im] = hbuf4[(row0 + 8 * im) * HS4 + (k0 >> 2) + kg];
                #pragma unroll
                for (int j = 0; j < 4; ++j) {
                    float4 w0 = wbuf4[(kg * 4 + j) * 32 + chh * 16 + c_l * 2 + 0];
                    float4 w1 = wbuf4[(kg * 4 + j) * 32 + chh * 16 + c_l * 2 + 1];
                    #pragma unroll
                    for (int im = 0; im < 8; ++im) {
                        float fv = (j == 0) ? f[im].x : (j == 1) ? f[im].y
                                 : (j == 2) ? f[im].z : f[im].w;
                        a[im][0] = fmaf(fv, w0.x, a[im][0]);
                        a[im][1] = fmaf(fv, w0.y, a[im][1]);
                        a[im][2] = fmaf(fv, w0.z, a[im][2]);
                        a[im][3] = fmaf(fv, w0.w, a[im][3]);
                        a[im][4] = fmaf(fv, w1.x, a[im][4]);
                        a[im][5] = fmaf(fv, w1.y, a[im][5]);
                        a[im][6] = fmaf(fv, w1.z, a[im][6]);
                        a[im][7] = fmaf(fv, w1.w, a[im][7]);
                    }
                }
            }
        }
        __syncthreads();
    }
    if (!skip && c_l < 6) {
        float* G = (wv >> 1) ? gself : gsrc;
        int lim = (wv >> 1) ? NOUT : N;
        #pragma unroll
        for (int im = 0; im < 8; ++im) {
            int n = base + row0 + 8 * im;
            if (n < lim) {
                *(float4*)(G + (size_t)n * CP + c_l * 8) =
                    make_float4(a[im][0], a[im][1], a[im][2], a[im][3]);
                *(float4*)(G + (size_t)n * CP + c_l * 8 + 4) =
                    make_float4(a[im][4], a[im][5], a[im][6], a[im][7]);
            }
        }
    }
}

// ---------------------------------------------------------------------------
// final v3 (R16): 256 thr = 4 waves, one node per wave (25000 -> 6250 blocks);
// unroll-4 gather of gsrc rows + fused log_softmax.
__global__ __launch_bounds__(256) void final_kernel(const float* __restrict__ gsrc,
        const float* __restrict__ gself, const int* __restrict__ row_ptr,
        const int* __restrict__ col, float* __restrict__ out) {
    int n = blockIdx.x * 4 + (threadIdx.x >> 6);
    int c = threadIdx.x & 63;
    int b = row_ptr[n], e = row_ptr[n + 1];
    float inv = 1.0f / (float)max(e - b, 1);
    float a0 = 0.f, a1 = 0.f, a2 = 0.f, a3 = 0.f;
    if (c < CP) {
        int j = b;
        for (; j + 3 < e; j += 4) {
            a0 += gsrc[(size_t)col[j]     * CP + c];
            a1 += gsrc[(size_t)col[j + 1] * CP + c];
            a2 += gsrc[(size_t)col[j + 2] * CP + c];
            a3 += gsrc[(size_t)col[j + 3] * CP + c];
        }
        for (; j < e; ++j) a0 += gsrc[(size_t)col[j] * CP + c];
    }
    float val = (c < COUT)
        ? (((a0 + a1) + (a2 + a3)) * inv + gself[(size_t)n * CP + c]) : -INFINITY;
    float m = val;
    #pragma unroll
    for (int off = 32; off > 0; off >>= 1) m = fmaxf(m, __shfl_xor(m, off, 64));
    float ex = (c < COUT) ? expf(val - m) : 0.f;
    float ssum = ex;
    #pragma unroll
    for (int off = 32; off > 0; off >>= 1) ssum += __shfl_xor(ssum, off, 64);
    if (c < COUT) out[(size_t)n * COUT + c] = val - m - logf(ssum);
}

// ---------------------------------------------------------------------------
extern "C" void kernel_launch(void* const* d_in, const int* in_sizes, int n_in,
                              void* d_out, int out_size, void* d_ws, size_t ws_size,
                              hipStream_t stream) {
    const float* x   = (const float*)d_in[0];
    const int*   ei  = (const int*)d_in[1];   // [2, E]: row 0 = src, row 1 = dst
    const int*   src = ei;
    const int*   dst = ei + E;
    const float* w1l = (const float*)d_in[3];
    const float* b1l = (const float*)d_in[4];
    const float* w1r = (const float*)d_in[5];
    const float* w2l = (const float*)d_in[6];
    const float* b2l = (const float*)d_in[7];
    const float* w2r = (const float*)d_in[8];
    float* out = (float*)d_out;

    // ws: ints [cnt N | row_ptr N+1 | cursor N | col E]
    // floats [agg1 N*CIN | gsrc N*CP | gself NOUT*CP | w2cat CH*128 | b2cat 128]
    int* cnt     = (int*)d_ws;
    int* row_ptr = cnt + N;
    int* cursor  = row_ptr + N + 1;
    int* col     = cursor + N;
    size_t intWords = (size_t)N + (N + 1) + N + E;
    intWords = (intWords + 3) & ~(size_t)3;
    float* agg1  = (float*)d_ws + intWords;
    float* gsrc  = agg1 + (size_t)N * CIN;
    float* gself = gsrc + (size_t)N * CP;
    float* w2cat = gself + (size_t)NOUT * CP;
    float* b2cat = w2cat + (size_t)CH * 128;
    // total ws ~38.4 MB (< 58.6 MB proven available)

    hipMemsetAsync(cnt, 0, (size_t)N * sizeof(int), stream);
    hist_pad    <<<EB + PADB, 256, 0, stream>>>(dst, cnt, w2l, w2r, b2l,
                                                w2cat, b2cat);
    scan_one    <<<NB, 256, 0, stream>>>(cnt, row_ptr, cursor);
    fill_kernel <<<EB, 256, 0, stream>>>(src, dst, cursor, col);
    gather1_kernel<<<N / 8, 256, 0, stream>>>(x, row_ptr, col, agg1);
    fused_gemm  <<<NT, 256, 0, stream>>>(agg1, x, w1l, b1l, w1r,
                                         w2cat, b2cat, gsrc, gself);
    final_kernel<<<NOUT / 4, 256, 0, stream>>>(gsrc, gself, row_ptr, col, out);
}